// Round 3
// baseline (3644.585 us; speedup 1.0000x reference)
//
#include <hip/hip_runtime.h>
#include <hip/hip_bf16.h>

// ============ DIAGNOSTIC ROUND: in-kernel REP loops to surface per-kernel ============
// ============ timings + counters in rocprof top-5. Set all REP_* to 1 to  ============
// ============ restore the fast configuration (R2 behavior).               ============
#define REP_PREP  3
#define REP_GRAM  3
#define REP_GACC  12
#define REP_STATS 32
#define REP_FEAT  12
#define REP_LOSS  24

#define C_IN   512
#define C_OUT  256
#define HW     16384      // 128*128
#define NIMG   8
#define PTOT   (NIMG * HW)  // 131072
#define MP     1024
#define TEMP_INV (1.0f / 0.07f)
#define BN_EPS   1e-5f
#define SPB    4          // samples per block in feature kernel
#define OGRP   4          // outputs per block in kstats
#define IGRP   4          // anchor rows per block in kloss
#define BK     64         // K-chunk per LDS stage in kgram
#define KCH    2048       // K per kgram block (32 stages) -> 64 chunks, 640 blocks
#define NCHUNK (PTOT / KCH)   // 64

typedef float  f32x4  __attribute__((ext_vector_type(4)));
typedef short  short8 __attribute__((ext_vector_type(8)));
typedef short  short4v __attribute__((ext_vector_type(4)));

// ws float layout
#define WS_S1   0                                 // s1p: per-plane sums, NIMG*C_IN
#define WS_G    (WS_S1 + NIMG * C_IN)
#define WS_W1P  (WS_G + C_IN * C_IN)
#define WS_B1P  (WS_W1P + C_IN * C_IN)
#define WS_CF   (WS_B1P + C_IN)
#define WS_XB_F (WS_CF + MP * C_OUT)
#define WS_NEED_FAST ((size_t)WS_XB_F * 4 + (size_t)PTOT * C_IN * 2)
#define WS_PART_F (WS_XB_F + PTOT * (C_IN / 2))   // xb occupies PTOT*C_IN/2 floats
#define NPART_F   (10 * NCHUNK * 128 * 128)       // 10 tiles x 64 chunks x 128x128 (40 MB)
#define WS_NEED_PART ((size_t)(WS_PART_F + NPART_F) * 4)

// ---------------- K0 (fast path): fused fp32->bf16 convert + per-plane sums ----------------
__global__ __launch_bounds__(256)
void kprep(const float* __restrict__ x, __hip_bfloat16* __restrict__ xb,
           float* __restrict__ s1p, float* __restrict__ out) {
    int plane = blockIdx.x;           // n*512 + c
    __shared__ float red[4];
    for (int rep = 0; rep < REP_PREP; ++rep) {
        if (plane == 0 && threadIdx.x == 0) *out = 0.f;
        const float4* p = (const float4*)(x + (size_t)plane * HW);
        short4v* q = (short4v*)(xb + (size_t)plane * HW);
        float acc = 0.f;
        for (int i = threadIdx.x; i < HW / 4; i += 256) {
            float4 v = p[i];
            acc += v.x + v.y + v.z + v.w;
            union { short4v s; __hip_bfloat162 h[2]; } u;
            u.h[0] = __float22bfloat162_rn(make_float2(v.x, v.y));
            u.h[1] = __float22bfloat162_rn(make_float2(v.z, v.w));
            q[i] = u.s;
        }
        for (int off = 32; off; off >>= 1) acc += __shfl_down(acc, off, 64);
        int lane = threadIdx.x & 63, wv = threadIdx.x >> 6;
        if (lane == 0) red[wv] = acc;
        __syncthreads();
        if (threadIdx.x == 0)
            s1p[plane] = red[0] + red[1] + red[2] + red[3];
        __syncthreads();
    }
}

// ---------------- K1 (fallback): per-plane sums only ----------------
__global__ __launch_bounds__(256)
void ksum(const float* __restrict__ x, float* __restrict__ s1p, float* __restrict__ out) {
    int plane = blockIdx.x;
    if (plane == 0 && threadIdx.x == 0) *out = 0.f;
    const float4* p = (const float4*)(x + (size_t)plane * HW);
    float acc = 0.f;
    for (int i = threadIdx.x; i < HW / 4; i += 256) {
        float4 v = p[i];
        acc += v.x + v.y + v.z + v.w;
    }
    for (int off = 32; off; off >>= 1) acc += __shfl_down(acc, off, 64);
    __shared__ float red[4];
    int lane = threadIdx.x & 63, wv = threadIdx.x >> 6;
    if (lane == 0) red[wv] = acc;
    __syncthreads();
    if (threadIdx.x == 0)
        s1p[plane] = red[0] + red[1] + red[2] + red[3];
}

// ---------------- K2: LDS-staged gram, single launch for all 10 tiles ----------------
__device__ const int TI2[10] = {0,1,2,3, 0,0,0,1,1,2};
__device__ const int TJ2[10] = {0,1,2,3, 1,2,3,2,3,3};

template<bool PART>
__global__ __launch_bounds__(256, 3)
void kgram2(const __hip_bfloat16* __restrict__ xb, float* __restrict__ G,
            float* __restrict__ Gp) {
    __shared__ __hip_bfloat16 buf[2][128 * BK];   // [0]=A, [1]=B ; 32 KB
    int tile  = blockIdx.x;           // 0..9
    int IT = TI2[tile] * 128;
    int JT = TJ2[tile] * 128;
    bool diag = (IT == JT);
    int bsel = diag ? 0 : 1;
    int chunk = blockIdx.y;           // 0..NCHUNK-1 ; n = chunk>>3, hw0 = (chunk&7)*KCH
    int n   = chunk >> 3;
    int hw0 = (chunk & 7) * KCH;
    int wave = threadIdx.x >> 6;
    int lane = threadIdx.x & 63;
    int wi = wave >> 1, wj = wave & 1;

    const __hip_bfloat16* gA = xb + ((size_t)n * C_IN + IT) * HW + hw0;
    const __hip_bfloat16* gB = xb + ((size_t)n * C_IN + JT) * HW + hw0;

    int rrel = lane >> 3;             // 0..7
    int slot = lane & 7;
    int m  = lane & 15;
    int kq = lane >> 4;               // 0..3

    for (int rep = 0; rep < REP_GRAM; ++rep) {
        f32x4 acc[4][4];
#pragma unroll
        for (int i = 0; i < 4; ++i)
#pragma unroll
            for (int j = 0; j < 4; ++j) acc[i][j] = {0.f, 0.f, 0.f, 0.f};

#pragma unroll 1
        for (int s = 0; s < KCH / BK; ++s) {
            int kk = s * BK;
#pragma unroll
            for (int i_ = 0; i_ < 4; ++i_) {
                int row = wave * 32 + i_ * 8 + rrel;
                int g   = slot ^ (row & 7);
                __builtin_amdgcn_global_load_lds(
                    (const __attribute__((address_space(1))) void*)
                        (gA + (size_t)row * HW + kk + g * 8),
                    (__attribute__((address_space(3))) void*)
                        (&buf[0][(wave * 32 + i_ * 8) * BK]),
                    16, 0, 0);
                if (!diag)
                    __builtin_amdgcn_global_load_lds(
                        (const __attribute__((address_space(1))) void*)
                            (gB + (size_t)row * HW + kk + g * 8),
                        (__attribute__((address_space(3))) void*)
                            (&buf[1][(wave * 32 + i_ * 8) * BK]),
                        16, 0, 0);
            }
            __syncthreads();               // drains vmcnt -> LDS valid for all waves
#pragma unroll
            for (int h = 0; h < 2; ++h) {
                short8 af[4], bf[4];
#pragma unroll
                for (int t_ = 0; t_ < 4; ++t_) {
                    int ra = wi * 64 + t_ * 16 + m;
                    int qa = (h * 4 + kq) ^ (ra & 7);
                    af[t_] = *(const short8*)&buf[0][ra * BK + qa * 8];
                    int rb = wj * 64 + t_ * 16 + m;
                    int qb = (h * 4 + kq) ^ (rb & 7);
                    bf[t_] = *(const short8*)&buf[bsel][rb * BK + qb * 8];
                }
#pragma unroll
                for (int i_ = 0; i_ < 4; ++i_)
#pragma unroll
                    for (int j_ = 0; j_ < 4; ++j_)
                        acc[i_][j_] = __builtin_amdgcn_mfma_f32_16x16x32_bf16(
                            af[i_], bf[j_], acc[i_][j_], 0, 0, 0);
            }
            __syncthreads();               // protect buffer reuse next stage
        }

        int r0 = (lane >> 4) * 4;
        int cc = lane & 15;
        if (PART) {
            float* P = Gp + ((size_t)tile * NCHUNK + chunk) * (128 * 128);
#pragma unroll
            for (int i = 0; i < 4; ++i)
#pragma unroll
                for (int j = 0; j < 4; ++j)
#pragma unroll
                    for (int r = 0; r < 4; ++r)
                        P[(wi * 64 + i * 16 + r0 + r) * 128 + (wj * 64 + j * 16 + cc)]
                            = acc[i][j][r];
        } else {
            if (rep == REP_GRAM - 1) {     // atomics are not idempotent: only last rep
#pragma unroll
                for (int i = 0; i < 4; ++i)
#pragma unroll
                    for (int j = 0; j < 4; ++j)
#pragma unroll
                        for (int r = 0; r < 4; ++r)
                            atomicAdd(&G[(size_t)(IT + wi * 64 + i * 16 + r0 + r) * C_IN
                                         + (JT + wj * 64 + j * 16 + cc)],
                                      acc[i][j][r]);
            }
        }
        __syncthreads();
    }
}

// ---------------- K2c: reduce NCHUNK chunk-partials per tile -> G (incl. transpose mirror) ----------------
__global__ __launch_bounds__(256)
void kgacc(const float* __restrict__ Gp, float* __restrict__ G) {
    int tile = blockIdx.x >> 4;       // 0..9
    int seg  = blockIdx.x & 15;       // 1024 elems per segment
    int IT = TI2[tile] * 128, JT = TJ2[tile] * 128;
    int e0 = seg * 1024 + threadIdx.x * 4;
    const float* base = Gp + (size_t)tile * NCHUNK * (128 * 128) + e0;
    for (int rep = 0; rep < REP_GACC; ++rep) {
        f32x4 a0 = {0,0,0,0}, a1 = {0,0,0,0}, a2 = {0,0,0,0}, a3 = {0,0,0,0};
        for (int ch = 0; ch < NCHUNK; ch += 4) {
            a0 += *(const f32x4*)(base + (size_t)(ch + 0) * (128 * 128));
            a1 += *(const f32x4*)(base + (size_t)(ch + 1) * (128 * 128));
            a2 += *(const f32x4*)(base + (size_t)(ch + 2) * (128 * 128));
            a3 += *(const f32x4*)(base + (size_t)(ch + 3) * (128 * 128));
        }
        f32x4 s = (a0 + a1) + (a2 + a3);
        int r = e0 >> 7, c = e0 & 127;
        *(f32x4*)(&G[(size_t)(IT + r) * C_IN + JT + c]) = s;
        if (IT != JT) {
#pragma unroll
            for (int k = 0; k < 4; ++k)
                G[(size_t)(JT + c + k) * C_IN + IT + r] = s[k];
        }
        asm volatile("" ::: "memory");
    }
}

// ---------------- K2b: mirror upper triangle of G into lower (atomic fallback only) ----------------
__global__ __launch_bounds__(256)
void kmirror(float* __restrict__ G) {
    int i = blockIdx.x;               // row
    for (int j = threadIdx.x; j < C_IN; j += 256) {
        if ((i >> 7) > (j >> 7))
            G[(size_t)i * C_IN + j] = G[(size_t)j * C_IN + i];
    }
}

// ---------------- K2-fallback: gram from fp32 with in-kernel cvt ----------------
__device__ inline short8 load_frag_f32(const float* p) {
    float4 a = *(const float4*)p;
    float4 b = *(const float4*)(p + 4);
    union { short8 s; __hip_bfloat162 h[4]; } u;
    u.h[0] = __float22bfloat162_rn(make_float2(a.x, a.y));
    u.h[1] = __float22bfloat162_rn(make_float2(a.z, a.w));
    u.h[2] = __float22bfloat162_rn(make_float2(b.x, b.y));
    u.h[3] = __float22bfloat162_rn(make_float2(b.z, b.w));
    return u.s;
}

__global__ __launch_bounds__(256)
void kgram_f32(const float* __restrict__ x, float* __restrict__ G) {
    int bz  = blockIdx.z;
    int n   = bz >> 2;
    int hw0 = (bz & 3) * 4096;
    int wave = threadIdx.x >> 6;
    int lane = threadIdx.x & 63;
    int wi = wave >> 1, wj = wave & 1;
    int I0 = blockIdx.x * 128 + wi * 64;
    int J0 = blockIdx.y * 128 + wj * 64;
    int m    = lane & 15;
    int koff = (lane >> 4) * 8;

    const float* baseA[4];
    const float* baseB[4];
#pragma unroll
    for (int t = 0; t < 4; ++t) {
        baseA[t] = x + ((size_t)n * C_IN + (I0 + t * 16 + m)) * HW + hw0 + koff;
        baseB[t] = x + ((size_t)n * C_IN + (J0 + t * 16 + m)) * HW + hw0 + koff;
    }

    f32x4 acc[4][4];
#pragma unroll
    for (int i = 0; i < 4; ++i)
#pragma unroll
        for (int j = 0; j < 4; ++j) acc[i][j] = {0.f, 0.f, 0.f, 0.f};

    for (int kk = 0; kk < 4096; kk += 32) {
        short8 afr[4], bfr[4];
#pragma unroll
        for (int t = 0; t < 4; ++t) {
            afr[t] = load_frag_f32(baseA[t] + kk);
            bfr[t] = load_frag_f32(baseB[t] + kk);
        }
#pragma unroll
        for (int i = 0; i < 4; ++i)
#pragma unroll
            for (int j = 0; j < 4; ++j)
                acc[i][j] = __builtin_amdgcn_mfma_f32_16x16x32_bf16(
                    afr[i], bfr[j], acc[i][j], 0, 0, 0);
    }

    int r0 = (lane >> 4) * 4;
    int cc = lane & 15;
#pragma unroll
    for (int i = 0; i < 4; ++i)
#pragma unroll
        for (int j = 0; j < 4; ++j)
#pragma unroll
            for (int r = 0; r < 4; ++r)
                atomicAdd(&G[(size_t)(I0 + i * 16 + r0 + r) * C_IN + (J0 + j * 16 + cc)],
                          acc[i][j][r]);
}

// ---------------- K3: BN stats + fold, OGRP outputs per block ----------------
__global__ __launch_bounds__(256)
void kstats(const float* __restrict__ w1, const float* __restrict__ b1,
            const float* __restrict__ gamma, const float* __restrict__ beta,
            const float* __restrict__ s1p, const float* __restrict__ G,
            float* __restrict__ w1p, float* __restrict__ b1p) {
    int o0 = blockIdx.x * OGRP;
    int tid = threadIdx.x;
    __shared__ float wr[OGRP][C_IN];          // 8 KB
    __shared__ float redd[4][OGRP];
    __shared__ float redq[4][OGRP];
    __shared__ float alpha_s[OGRP];

    for (int rep = 0; rep < REP_STATS; ++rep) {
        for (int idx = tid; idx < OGRP * C_IN; idx += 256) {
            int og = idx >> 9, c = idx & (C_IN - 1);
            wr[og][c] = w1[(size_t)(o0 + og) * C_IN + c];
        }
        __syncthreads();

        float dot1[OGRP], quad[OGRP];
#pragma unroll
        for (int og = 0; og < OGRP; ++og) { dot1[og] = 0.f; quad[og] = 0.f; }

        for (int c = tid; c < C_IN; c += 256) {
            const float* gr = G + (size_t)c * C_IN;
            float s1c = 0.f;
#pragma unroll
            for (int nn = 0; nn < NIMG; ++nn) s1c += s1p[nn * C_IN + c];
            float inner[OGRP];
#pragma unroll
            for (int og = 0; og < OGRP; ++og) inner[og] = 0.f;
            for (int d = 0; d < C_IN; d += 4) {
                float4 gv = *(const float4*)(gr + d);
#pragma unroll
                for (int og = 0; og < OGRP; ++og) {
                    float4 wv = *(const float4*)(&wr[og][d]);
                    inner[og] += gv.x * wv.x + gv.y * wv.y + gv.z * wv.z + gv.w * wv.w;
                }
            }
#pragma unroll
            for (int og = 0; og < OGRP; ++og) {
                float wc = wr[og][c];
                quad[og] += inner[og] * wc;
                dot1[og] += s1c * wc;
            }
        }
#pragma unroll
        for (int og = 0; og < OGRP; ++og) {
            for (int off = 32; off; off >>= 1) {
                dot1[og] += __shfl_down(dot1[og], off, 64);
                quad[og] += __shfl_down(quad[og], off, 64);
            }
        }
        int lane = tid & 63, wv = tid >> 6;
        if (lane == 0) {
#pragma unroll
            for (int og = 0; og < OGRP; ++og) { redd[wv][og] = dot1[og]; redq[wv][og] = quad[og]; }
        }
        __syncthreads();
        if (tid < OGRP) {
            int og = tid;
            float d1 = redd[0][og] + redd[1][og] + redd[2][og] + redd[3][og];
            float q  = redq[0][og] + redq[1][og] + redq[2][og] + redq[3][og];
            float b  = b1[o0 + og];
            float mean = d1 / (float)PTOT + b;
            float eh2  = (q + 2.f * b * d1) / (float)PTOT + b * b;
            float var  = eh2 - mean * mean;
            float al   = gamma[o0 + og] * rsqrtf(var + BN_EPS);
            alpha_s[og] = al;
            b1p[o0 + og] = beta[o0 + og] + al * (b - mean);
        }
        __syncthreads();
        for (int idx = tid; idx < OGRP * C_IN; idx += 256) {
            int og = idx >> 9, c = idx & (C_IN - 1);
            w1p[(size_t)(o0 + og) * C_IN + c] = alpha_s[og] * wr[og][c];
        }
        __syncthreads();
    }
}

// ---------------- K4: features at sampled pixels (float4 weight reads) ----------------
__global__ __launch_bounds__(256)
void kfeat(const float* __restrict__ x, const float* __restrict__ w1p,
           const float* __restrict__ b1p, const float* __restrict__ w2,
           const float* __restrict__ b2, const int* __restrict__ batch_idx,
           const int* __restrict__ pix_idx, float* __restrict__ cf,
           int M, int T, int n_view) {
    __shared__ float xcol[SPB][C_IN];
    __shared__ float h1[SPB][C_IN];
    __shared__ float fl[SPB][C_OUT];
    int tid = threadIdx.x;
    int m0 = blockIdx.x * SPB;

    for (int rep = 0; rep < REP_FEAT; ++rep) {
        for (int idx = tid; idx < SPB * C_IN; idx += 256) {
            int s = idx >> 9, c = idx & (C_IN - 1);
            int mm = m0 + s;
            float v = 0.f;
            if (mm < M) {
                int t = mm % T, vv = mm / T;          // cf row m = v*T + t
                int n = batch_idx[t];
                int pix = pix_idx[t * n_view + vv];
                v = x[((size_t)n * C_IN + c) * HW + pix];
            }
            xcol[s][c] = v;
        }
        __syncthreads();

        for (int o = tid; o < C_IN; o += 256) {
            float acc[SPB];
            float bb = b1p[o];
#pragma unroll
            for (int s = 0; s < SPB; ++s) acc[s] = bb;
            const float* wrp = w1p + (size_t)o * C_IN;
            for (int c = 0; c < C_IN; c += 4) {
                float4 w = *(const float4*)(wrp + c);
#pragma unroll
                for (int s = 0; s < SPB; ++s) {
                    float4 xv = *(const float4*)(&xcol[s][c]);
                    acc[s] += w.x * xv.x + w.y * xv.y + w.z * xv.z + w.w * xv.w;
                }
            }
#pragma unroll
            for (int s = 0; s < SPB; ++s) h1[s][o] = fmaxf(acc[s], 0.f);
        }
        __syncthreads();

        {
            int j = tid;
            float acc[SPB];
            float bb = b2[j];
#pragma unroll
            for (int s = 0; s < SPB; ++s) acc[s] = bb;
            const float* wrp = w2 + (size_t)j * C_IN;
            for (int o = 0; o < C_IN; o += 4) {
                float4 w = *(const float4*)(wrp + o);
#pragma unroll
                for (int s = 0; s < SPB; ++s) {
                    float4 hv = *(const float4*)(&h1[s][o]);
                    acc[s] += w.x * hv.x + w.y * hv.y + w.z * hv.z + w.w * hv.w;
                }
            }
#pragma unroll
            for (int s = 0; s < SPB; ++s) fl[s][j] = acc[s];
        }
        __syncthreads();

        int wv = tid >> 6, lane = tid & 63;
        {
            float sq = 0.f;
#pragma unroll
            for (int k = 0; k < 4; ++k) { float v = fl[wv][lane + 64 * k]; sq += v * v; }
            for (int off = 32; off; off >>= 1) sq += __shfl_down(sq, off, 64);
            float nrm = __shfl(sq, 0, 64);
            float rinv = 1.f / fmaxf(sqrtf(nrm), 1e-12f);
            int mm = m0 + wv;
            if (mm < M) {
#pragma unroll
                for (int k = 0; k < 4; ++k)
                    cf[(size_t)mm * C_OUT + lane + 64 * k] = fl[wv][lane + 64 * k] * rinv;
            }
        }
        __syncthreads();
    }
}

// ---------------- K5: fused logits + loss, IGRP anchor rows per block ----------------
__global__ __launch_bounds__(256)
void kloss(const float* __restrict__ cf, const int* __restrict__ y_cls,
           float* __restrict__ out, float* __restrict__ dummy, int M, int T) {
    int i0 = blockIdx.x * IGRP;
    int tid = threadIdx.x;
    __shared__ float ci[IGRP][C_OUT];         // 4 KB
    __shared__ float row[IGRP][MP];           // 16 KB
    __shared__ int   lbl[MP];                 // 4 KB
    __shared__ float redl[IGRP];
    int lane = tid & 63, wv = tid >> 6;

    for (int rep = 0; rep < REP_LOSS; ++rep) {
        float* tgt = (rep == REP_LOSS - 1) ? out : (dummy + blockIdx.x);

        for (int idx = tid; idx < IGRP * C_OUT; idx += 256) {
            int g = idx >> 8, c = idx & (C_OUT - 1);
            int ii = i0 + g;
            ci[g][c] = (ii < M) ? cf[(size_t)ii * C_OUT + c] : 0.f;
        }
        for (int j = tid; j < M; j += 256) lbl[j] = y_cls[j % T];
        __syncthreads();

        for (int j = tid; j < M; j += 256) {
            const float* cj = cf + (size_t)j * C_OUT;
            float acc[IGRP];
#pragma unroll
            for (int g = 0; g < IGRP; ++g) acc[g] = 0.f;
            for (int c = 0; c < C_OUT; c += 4) {
                float4 v = *(const float4*)(cj + c);
#pragma unroll
                for (int g = 0; g < IGRP; ++g) {
                    float4 cv = *(const float4*)(&ci[g][c]);
                    acc[g] += cv.x * v.x + cv.y * v.y + cv.z * v.z + cv.w * v.w;
                }
            }
#pragma unroll
            for (int g = 0; g < IGRP; ++g) row[g][j] = acc[g] * TEMP_INV;
        }
        __syncthreads();

        for (int g = wv; g < IGRP; g += 4) {
            int i = i0 + g;
            if (i < M) {
                int lbl_i = lbl[i];
                const float* r = row[g];

                float mx = -1e30f;
                for (int j = lane; j < M; j += 64) mx = fmaxf(mx, r[j]);
                for (int off = 32; off; off >>= 1) mx = fmaxf(mx, __shfl_down(mx, off, 64));
                mx = __shfl(mx, 0, 64);

                float neg = 0.f;
                for (int j = lane; j < M; j += 64)
                    if (lbl[j] != lbl_i) neg += expf(r[j] - mx);
                for (int off = 32; off; off >>= 1) neg += __shfl_down(neg, off, 64);
                neg = __shfl(neg, 0, 64);

                float pos = 0.f; int cnt = 0;
                for (int j = lane; j < M; j += 64) {
                    if (lbl[j] == lbl_i && j != i) {
                        float l = r[j] - mx;
                        pos += l - logf(expf(l) + neg);
                        cnt++;
                    }
                }
                for (int off = 32; off; off >>= 1) {
                    pos += __shfl_down(pos, off, 64);
                    cnt += __shfl_down(cnt, off, 64);
                }
                if (lane == 0) redl[g] = -pos / ((float)cnt + 1e-6f);
            } else if (lane == 0) redl[g] = 0.f;
        }
        __syncthreads();
        if (tid == 0) {
            float s = 0.f;
            for (int g = 0; g < IGRP; ++g) s += redl[g];
            atomicAdd(tgt, s * (0.5f / (float)M));
        }
        __syncthreads();
    }
}

extern "C" void kernel_launch(void* const* d_in, const int* in_sizes, int n_in,
                              void* d_out, int out_size, void* d_ws, size_t ws_size,
                              hipStream_t stream) {
    const float* x     = (const float*)d_in[0];
    const float* w1    = (const float*)d_in[1];
    const float* b1    = (const float*)d_in[2];
    const float* gamma = (const float*)d_in[3];
    const float* beta  = (const float*)d_in[4];
    const float* w2    = (const float*)d_in[5];
    const float* b2    = (const float*)d_in[6];
    const int* batch_idx = (const int*)d_in[7];
    const int* pix_idx   = (const int*)d_in[8];
    const int* y_cls     = (const int*)d_in[9];

    int T = in_sizes[7];
    int M = in_sizes[8];
    int n_view = M / T;

    float* ws  = (float*)d_ws;
    float* s1p = ws + WS_S1;
    float* G   = ws + WS_G;
    float* w1p = ws + WS_W1P;
    float* b1p = ws + WS_B1P;
    float* cf  = ws + WS_CF;
    __hip_bfloat16* xb = (__hip_bfloat16*)(ws + WS_XB_F);
    float* Gpart = ws + WS_PART_F;

    if (ws_size >= WS_NEED_PART) {
        kprep<<<NIMG * C_IN, 256, 0, stream>>>(x, xb, s1p, (float*)d_out);
        kgram2<true><<<dim3(10, NCHUNK), 256, 0, stream>>>(xb, G, Gpart);
        kgacc<<<160, 256, 0, stream>>>(Gpart, G);
    } else if (ws_size >= WS_NEED_FAST) {
        hipMemsetAsync(G, 0, (size_t)(C_IN * C_IN) * sizeof(float), stream);
        kprep<<<NIMG * C_IN, 256, 0, stream>>>(x, xb, s1p, (float*)d_out);
        kgram2<false><<<dim3(10, NCHUNK), 256, 0, stream>>>(xb, G, nullptr);
        kmirror<<<C_IN, 256, 0, stream>>>(G);
    } else {
        hipMemsetAsync(G, 0, (size_t)(C_IN * C_IN) * sizeof(float), stream);
        ksum<<<NIMG * C_IN, 256, 0, stream>>>(x, s1p, (float*)d_out);
        kgram_f32<<<dim3(4, 4, 32), 256, 0, stream>>>(x, G);
    }
    kstats<<<C_IN / OGRP, 256, 0, stream>>>(w1, b1, gamma, beta, s1p, G, w1p, b1p);
    kfeat<<<(M + SPB - 1) / SPB, 256, 0, stream>>>(x, w1p, b1p, w2, b2,
                                                   batch_idx, pix_idx, cf, M, T, n_view);
    // dummy target for non-final kloss reps: reuse Gpart region (dead after kstats)
    kloss<<<(M + IGRP - 1) / IGRP, 256, 0, stream>>>(cf, y_cls, (float*)d_out,
                                                     Gpart, M, T);
}

// Round 5
// 622.351 us; speedup vs baseline: 5.8562x; 5.8562x over previous
//
#include <hip/hip_runtime.h>
#include <hip/hip_bf16.h>

#define C_IN   512
#define C_OUT  256
#define HW     16384      // 128*128
#define NIMG   8
#define PTOT   (NIMG * HW)  // 131072
#define MP     1024
#define TEMP_INV (1.0f / 0.07f)
#define BN_EPS   1e-5f
#define SPB    4          // samples per block in feature kernel
#define IGRP   4          // anchor rows per block in kloss
#define BK     64         // K-chunk per LDS stage in kgram
#define KCH    2048       // K per kgram block (32 stages) -> 64 chunks, 640 blocks
#define NCHUNK (PTOT / KCH)   // 64
#define NTILE  10

typedef float  f32x4  __attribute__((ext_vector_type(4)));
typedef short  short8 __attribute__((ext_vector_type(8)));
typedef short  short4v __attribute__((ext_vector_type(4)));

// ws float layout
#define WS_S1    0                                // s1p: per-plane sums, NIMG*C_IN
#define WS_G     (WS_S1 + NIMG * C_IN)
#define WS_QUAD  (WS_G + C_IN * C_IN)             // quad[o] partial accumulator
#define WS_DOT1  (WS_QUAD + C_IN)                 // dot1[o] partial accumulator
#define WS_ALPHA (WS_DOT1 + C_IN)
#define WS_B1P   (WS_ALPHA + C_IN)
#define WS_CF    (WS_B1P + C_IN)
#define WS_XB_F  (WS_CF + MP * C_OUT)
#define WS_NEED_FAST ((size_t)WS_XB_F * 4 + (size_t)PTOT * C_IN * 2)
#define WS_PART_F (WS_XB_F + PTOT * (C_IN / 2))   // xb occupies PTOT*C_IN/2 floats
#define NPART_F   (NTILE * NCHUNK * 128 * 128)    // 40 MB of partial tiles
#define WS_NEED_PART ((size_t)(WS_PART_F + NPART_F) * 4)

// ---------------- K0: fused fp32->bf16 convert + per-plane sums (+zero scratch) ----------------
__global__ __launch_bounds__(256)
void kprep(const float* __restrict__ x, __hip_bfloat16* __restrict__ xb,
           float* __restrict__ s1p, float* __restrict__ quadb,
           float* __restrict__ dot1b, float* __restrict__ out) {
    int plane = blockIdx.x;           // n*512 + c
    if (plane == 0) {                 // zero accumulators consumed later in the stream
        if (threadIdx.x == 0) *out = 0.f;
        quadb[threadIdx.x] = 0.f; quadb[256 + threadIdx.x] = 0.f;
        dot1b[threadIdx.x] = 0.f; dot1b[256 + threadIdx.x] = 0.f;
    }
    const float4* p = (const float4*)(x + (size_t)plane * HW);
    short4v* q = (short4v*)(xb + (size_t)plane * HW);
    float acc = 0.f;
    for (int i = threadIdx.x; i < HW / 4; i += 256) {
        float4 v = p[i];
        acc += v.x + v.y + v.z + v.w;
        union { short4v s; __hip_bfloat162 h[2]; } u;
        u.h[0] = __float22bfloat162_rn(make_float2(v.x, v.y));
        u.h[1] = __float22bfloat162_rn(make_float2(v.z, v.w));
        q[i] = u.s;
    }
    for (int off = 32; off; off >>= 1) acc += __shfl_down(acc, off, 64);
    __shared__ float red[4];
    int lane = threadIdx.x & 63, wv = threadIdx.x >> 6;
    if (lane == 0) red[wv] = acc;
    __syncthreads();
    if (threadIdx.x == 0)
        s1p[plane] = red[0] + red[1] + red[2] + red[3];
}

// ---------------- K1 (fallback): per-plane sums only ----------------
__global__ __launch_bounds__(256)
void ksum(const float* __restrict__ x, float* __restrict__ s1p,
          float* __restrict__ quadb, float* __restrict__ dot1b,
          float* __restrict__ out) {
    int plane = blockIdx.x;
    if (plane == 0) {
        if (threadIdx.x == 0) *out = 0.f;
        quadb[threadIdx.x] = 0.f; quadb[256 + threadIdx.x] = 0.f;
        dot1b[threadIdx.x] = 0.f; dot1b[256 + threadIdx.x] = 0.f;
    }
    const float4* p = (const float4*)(x + (size_t)plane * HW);
    float acc = 0.f;
    for (int i = threadIdx.x; i < HW / 4; i += 256) {
        float4 v = p[i];
        acc += v.x + v.y + v.z + v.w;
    }
    for (int off = 32; off; off >>= 1) acc += __shfl_down(acc, off, 64);
    __shared__ float red[4];
    int lane = threadIdx.x & 63, wv = threadIdx.x >> 6;
    if (lane == 0) red[wv] = acc;
    __syncthreads();
    if (threadIdx.x == 0)
        s1p[plane] = red[0] + red[1] + red[2] + red[3];
}

__device__ const int TI2[NTILE] = {0,1,2,3, 0,0,0,1,1,2};
__device__ const int TJ2[NTILE] = {0,1,2,3, 1,2,3,2,3,3};

// ---------------- K2: gram, 2-phase double-buffered (T3-minimum skeleton) ----------------
// STAGE(next) issued BEFORE compute(cur); counted vmcnt(8) + raw s_barrier keep
// next-stage loads in flight under current MFMA (never drain to 0 mid-loop).
// XCD swizzle: all 10 tiles of a chunk -> same XCD (2 MB working set < 4 MB L2).
// Diag tiles dual-stage (gB==gA: B-loads hit L1 on just-fetched lines).
// sched_barrier(0) after each hand-written waitcnt (rule #18 insurance).
__global__ __launch_bounds__(256, 2)
void kgram3(const __hip_bfloat16* __restrict__ xb, float* __restrict__ Gp) {
    __shared__ __hip_bfloat16 Ab[2][128 * BK];   // 32 KB
    __shared__ __hip_bfloat16 Bb[2][128 * BK];   // 32 KB
    int bid  = blockIdx.x;            // 640 = 8 xcd * 8 cgrp * 10 tiles
    int xcd  = bid & 7;
    int r    = bid >> 3;
    int tile = r % NTILE;
    int chunk = (r / NTILE) * 8 + xcd;           // chunk % 8 == xcd
    int IT = TI2[tile] * 128, JT = TJ2[tile] * 128;
    int n   = chunk >> 3;
    int hw0 = (chunk & 7) * KCH;
    int wave = threadIdx.x >> 6, lane = threadIdx.x & 63;
    int wi = wave >> 1, wj = wave & 1;
    const __hip_bfloat16* gA = xb + ((size_t)n * C_IN + IT) * HW + hw0;
    const __hip_bfloat16* gB = xb + ((size_t)n * C_IN + JT) * HW + hw0;
    int rrel = lane >> 3, slot = lane & 7;
    int m = lane & 15, kq = lane >> 4;

    f32x4 acc[4][4];
#pragma unroll
    for (int i = 0; i < 4; ++i)
#pragma unroll
        for (int j = 0; j < 4; ++j) acc[i][j] = {0.f, 0.f, 0.f, 0.f};

    auto stage = [&](int sel, int kk_) {
#pragma unroll
        for (int i_ = 0; i_ < 4; ++i_) {
            int row = wave * 32 + i_ * 8 + rrel;
            int g   = slot ^ (row & 7);
            __builtin_amdgcn_global_load_lds(
                (const __attribute__((address_space(1))) void*)
                    (gA + (size_t)row * HW + kk_ + g * 8),
                (__attribute__((address_space(3))) void*)
                    (&Ab[sel][(wave * 32 + i_ * 8) * BK]), 16, 0, 0);
            __builtin_amdgcn_global_load_lds(
                (const __attribute__((address_space(1))) void*)
                    (gB + (size_t)row * HW + kk_ + g * 8),
                (__attribute__((address_space(3))) void*)
                    (&Bb[sel][(wave * 32 + i_ * 8) * BK]), 16, 0, 0);
        }
    };
    auto compute = [&](int cur) {
#pragma unroll
        for (int h = 0; h < 2; ++h) {
            short8 af[4], bf[4];
#pragma unroll
            for (int t_ = 0; t_ < 4; ++t_) {
                int ra = wi * 64 + t_ * 16 + m;
                int qa = (h * 4 + kq) ^ (ra & 7);
                af[t_] = *(const short8*)&Ab[cur][ra * BK + qa * 8];
                int rb = wj * 64 + t_ * 16 + m;
                int qb = (h * 4 + kq) ^ (rb & 7);
                bf[t_] = *(const short8*)&Bb[cur][rb * BK + qb * 8];
            }
#pragma unroll
            for (int i_ = 0; i_ < 4; ++i_)
#pragma unroll
                for (int j_ = 0; j_ < 4; ++j_)
                    acc[i_][j_] = __builtin_amdgcn_mfma_f32_16x16x32_bf16(
                        af[i_], bf[j_], acc[i_][j_], 0, 0, 0);
        }
    };

    constexpr int NS = KCH / BK;      // 32
    stage(0, 0);
#pragma unroll 1
    for (int s = 0; s < NS - 1; ++s) {
        int cur = s & 1;
        stage(cur ^ 1, (s + 1) * BK);                  // prefetch next stage
        asm volatile("s_waitcnt vmcnt(8)" ::: "memory"); // wait CURRENT stage only
        __builtin_amdgcn_sched_barrier(0);
        __builtin_amdgcn_s_barrier();
        compute(cur);
        __builtin_amdgcn_s_barrier();                  // protect buf reuse
    }
    asm volatile("s_waitcnt vmcnt(0)" ::: "memory");
    __builtin_amdgcn_sched_barrier(0);
    __builtin_amdgcn_s_barrier();
    compute((NS - 1) & 1);

    int r0 = (lane >> 4) * 4;
    int cc = lane & 15;
    float* P = Gp + ((size_t)tile * NCHUNK + chunk) * (128 * 128);
#pragma unroll
    for (int i = 0; i < 4; ++i)
#pragma unroll
        for (int j = 0; j < 4; ++j)
#pragma unroll
            for (int rr = 0; rr < 4; ++rr)
                P[(wi * 64 + i * 16 + r0 + rr) * 128 + (wj * 64 + j * 16 + cc)]
                    = acc[i][j][rr];
}

// ---------------- K2c: reduce NCHUNK chunk-partials per tile -> G (incl. mirror) ----------------
__global__ __launch_bounds__(256)
void kgacc(const float* __restrict__ Gp, float* __restrict__ G) {
    int tile = blockIdx.x >> 4;       // 0..9
    int seg  = blockIdx.x & 15;
    int IT = TI2[tile] * 128, JT = TJ2[tile] * 128;
    int e0 = seg * 1024 + threadIdx.x * 4;
    const float* base = Gp + (size_t)tile * NCHUNK * (128 * 128) + e0;
    f32x4 a0 = {0,0,0,0}, a1 = {0,0,0,0}, a2 = {0,0,0,0}, a3 = {0,0,0,0};
    for (int ch = 0; ch < NCHUNK; ch += 4) {
        a0 += *(const f32x4*)(base + (size_t)(ch + 0) * (128 * 128));
        a1 += *(const f32x4*)(base + (size_t)(ch + 1) * (128 * 128));
        a2 += *(const f32x4*)(base + (size_t)(ch + 2) * (128 * 128));
        a3 += *(const f32x4*)(base + (size_t)(ch + 3) * (128 * 128));
    }
    f32x4 s = (a0 + a1) + (a2 + a3);
    int rr = e0 >> 7, c = e0 & 127;
    *(f32x4*)(&G[(size_t)(IT + rr) * C_IN + JT + c]) = s;
    if (IT != JT) {
#pragma unroll
        for (int k = 0; k < 4; ++k)
            G[(size_t)(JT + c + k) * C_IN + IT + rr] = s[k];
    }
}

// ---------------- K2 (middle fallback): atomic gram, serial 2-barrier ----------------
__global__ __launch_bounds__(256, 3)
void kgram_at(const __hip_bfloat16* __restrict__ xb, float* __restrict__ G) {
    __shared__ __hip_bfloat16 buf[2][128 * BK];
    int tile  = blockIdx.x;
    int IT = TI2[tile] * 128, JT = TJ2[tile] * 128;
    bool diag = (IT == JT);
    int bsel = diag ? 0 : 1;
    int chunk = blockIdx.y;
    int n   = chunk >> 3;
    int hw0 = (chunk & 7) * KCH;
    int wave = threadIdx.x >> 6, lane = threadIdx.x & 63;
    int wi = wave >> 1, wj = wave & 1;
    const __hip_bfloat16* gA = xb + ((size_t)n * C_IN + IT) * HW + hw0;
    const __hip_bfloat16* gB = xb + ((size_t)n * C_IN + JT) * HW + hw0;
    int rrel = lane >> 3, slot = lane & 7;
    int m = lane & 15, kq = lane >> 4;

    f32x4 acc[4][4];
#pragma unroll
    for (int i = 0; i < 4; ++i)
#pragma unroll
        for (int j = 0; j < 4; ++j) acc[i][j] = {0.f, 0.f, 0.f, 0.f};

#pragma unroll 1
    for (int s = 0; s < KCH / BK; ++s) {
        int kk = s * BK;
#pragma unroll
        for (int i_ = 0; i_ < 4; ++i_) {
            int row = wave * 32 + i_ * 8 + rrel;
            int g   = slot ^ (row & 7);
            __builtin_amdgcn_global_load_lds(
                (const __attribute__((address_space(1))) void*)
                    (gA + (size_t)row * HW + kk + g * 8),
                (__attribute__((address_space(3))) void*)
                    (&buf[0][(wave * 32 + i_ * 8) * BK]), 16, 0, 0);
            if (!diag)
                __builtin_amdgcn_global_load_lds(
                    (const __attribute__((address_space(1))) void*)
                        (gB + (size_t)row * HW + kk + g * 8),
                    (__attribute__((address_space(3))) void*)
                        (&buf[1][(wave * 32 + i_ * 8) * BK]), 16, 0, 0);
        }
        __syncthreads();
#pragma unroll
        for (int h = 0; h < 2; ++h) {
            short8 af[4], bf[4];
#pragma unroll
            for (int t_ = 0; t_ < 4; ++t_) {
                int ra = wi * 64 + t_ * 16 + m;
                int qa = (h * 4 + kq) ^ (ra & 7);
                af[t_] = *(const short8*)&buf[0][ra * BK + qa * 8];
                int rb = wj * 64 + t_ * 16 + m;
                int qb = (h * 4 + kq) ^ (rb & 7);
                bf[t_] = *(const short8*)&buf[bsel][rb * BK + qb * 8];
            }
#pragma unroll
            for (int i_ = 0; i_ < 4; ++i_)
#pragma unroll
                for (int j_ = 0; j_ < 4; ++j_)
                    acc[i_][j_] = __builtin_amdgcn_mfma_f32_16x16x32_bf16(
                        af[i_], bf[j_], acc[i_][j_], 0, 0, 0);
        }
        __syncthreads();
    }

    int r0 = (lane >> 4) * 4;
    int cc = lane & 15;
#pragma unroll
    for (int i = 0; i < 4; ++i)
#pragma unroll
        for (int j = 0; j < 4; ++j)
#pragma unroll
            for (int rr = 0; rr < 4; ++rr)
                atomicAdd(&G[(size_t)(IT + wi * 64 + i * 16 + r0 + rr) * C_IN
                             + (JT + wj * 64 + j * 16 + cc)],
                          acc[i][j][rr]);
}

// ---------------- K2b: mirror (atomic fallback only) ----------------
__global__ __launch_bounds__(256)
void kmirror(float* __restrict__ G) {
    int i = blockIdx.x;
    for (int j = threadIdx.x; j < C_IN; j += 256) {
        if ((i >> 7) > (j >> 7))
            G[(size_t)i * C_IN + j] = G[(size_t)j * C_IN + i];
    }
}

// ---------------- K2-fallback: gram from fp32 with in-kernel cvt ----------------
__device__ inline short8 load_frag_f32(const float* p) {
    float4 a = *(const float4*)p;
    float4 b = *(const float4*)(p + 4);
    union { short8 s; __hip_bfloat162 h[4]; } u;
    u.h[0] = __float22bfloat162_rn(make_float2(a.x, a.y));
    u.h[1] = __float22bfloat162_rn(make_float2(a.z, a.w));
    u.h[2] = __float22bfloat162_rn(make_float2(b.x, b.y));
    u.h[3] = __float22bfloat162_rn(make_float2(b.z, b.w));
    return u.s;
}

__global__ __launch_bounds__(256)
void kgram_f32(const float* __restrict__ x, float* __restrict__ G) {
    int bz  = blockIdx.z;
    int n   = bz >> 2;
    int hw0 = (bz & 3) * 4096;
    int wave = threadIdx.x >> 6, lane = threadIdx.x & 63;
    int wi = wave >> 1, wj = wave & 1;
    int I0 = blockIdx.x * 128 + wi * 64;
    int J0 = blockIdx.y * 128 + wj * 64;
    int m    = lane & 15;
    int koff = (lane >> 4) * 8;

    const float* baseA[4];
    const float* baseB[4];
#pragma unroll
    for (int t = 0; t < 4; ++t) {
        baseA[t] = x + ((size_t)n * C_IN + (I0 + t * 16 + m)) * HW + hw0 + koff;
        baseB[t] = x + ((size_t)n * C_IN + (J0 + t * 16 + m)) * HW + hw0 + koff;
    }

    f32x4 acc[4][4];
#pragma unroll
    for (int i = 0; i < 4; ++i)
#pragma unroll
        for (int j = 0; j < 4; ++j) acc[i][j] = {0.f, 0.f, 0.f, 0.f};

    for (int kk = 0; kk < 4096; kk += 32) {
        short8 afr[4], bfr[4];
#pragma unroll
        for (int t = 0; t < 4; ++t) {
            afr[t] = load_frag_f32(baseA[t] + kk);
            bfr[t] = load_frag_f32(baseB[t] + kk);
        }
#pragma unroll
        for (int i = 0; i < 4; ++i)
#pragma unroll
            for (int j = 0; j < 4; ++j)
                acc[i][j] = __builtin_amdgcn_mfma_f32_16x16x32_bf16(
                    afr[i], bfr[j], acc[i][j], 0, 0, 0);
    }

    int r0 = (lane >> 4) * 4;
    int cc = lane & 15;
#pragma unroll
    for (int i = 0; i < 4; ++i)
#pragma unroll
        for (int j = 0; j < 4; ++j)
#pragma unroll
            for (int rr = 0; rr < 4; ++rr)
                atomicAdd(&G[(size_t)(I0 + i * 16 + r0 + rr) * C_IN + (J0 + j * 16 + cc)],
                          acc[i][j][rr]);
}

// ---------------- K3a: quad/dot1 partials, 512 blocks (latency fix for old kstats) ----------------
// Block (ci,oi): 32x16 (c,o) patch. Y[c][o]=G[c]·w1[o] in regs, immediately reduced:
// quad[o] += Y[c][o]*w1[o][c]; dot1[o] += s1tot[c]*w1[o][c].
__global__ __launch_bounds__(256)
void kquad(const float* __restrict__ G, const float* __restrict__ w1,
           const float* __restrict__ s1p, float* __restrict__ quadb,
           float* __restrict__ dot1b) {
    __shared__ float Wt[16][516];     // 33 KB; +4 pad keeps rows on distinct banks
    __shared__ float pq[16], pd1[16], s1t[32];
    int tid = threadIdx.x;
    int c0 = blockIdx.x * 32, o0 = blockIdx.y * 16;

    for (int idx = tid; idx < 16 * 128; idx += 256) {
        int row = idx >> 7, c4 = idx & 127;
        *(f32x4*)&Wt[row][c4 * 4] =
            *(const f32x4*)(w1 + (size_t)(o0 + row) * C_IN + c4 * 4);
    }
    if (tid < 16) { pq[tid] = 0.f; pd1[tid] = 0.f; }
    if (tid < 32) {
        float s = 0.f;
#pragma unroll
        for (int nn = 0; nn < NIMG; ++nn) s += s1p[nn * C_IN + c0 + tid];
        s1t[tid] = s;
    }
    __syncthreads();

    int c_l = tid >> 3;               // 0..31 (8 lanes share a c -> G broadcast)
    int og  = tid & 7;                // o = o0 + og + 8k, k in 0..1
    const float* Gr = G + (size_t)(c0 + c_l) * C_IN;

    f32x4 y4[2];
#pragma unroll
    for (int k = 0; k < 2; ++k) y4[k] = {0.f, 0.f, 0.f, 0.f};
#pragma unroll 4
    for (int d = 0; d < C_IN; d += 4) {
        f32x4 g4 = *(const f32x4*)(Gr + d);
#pragma unroll
        for (int k = 0; k < 2; ++k)
            y4[k] += g4 * (*(const f32x4*)&Wt[og + 8 * k][d]);
    }

    int c = c0 + c_l;
#pragma unroll
    for (int k = 0; k < 2; ++k) {
        int ol = og + 8 * k;
        float y  = y4[k][0] + y4[k][1] + y4[k][2] + y4[k][3];
        float wc = Wt[ol][c];
        atomicAdd(&pq[ol],  y * wc);
        atomicAdd(&pd1[ol], s1t[c_l] * wc);
    }
    __syncthreads();
    if (tid < 16) {
        atomicAdd(&quadb[o0 + tid], pq[tid]);
        atomicAdd(&dot1b[o0 + tid], pd1[tid]);
    }
}

// ---------------- K3b: finish BN fold -> alpha, b1p (w1p never materialized) ----------------
__global__ __launch_bounds__(512)
void kfin(const float* __restrict__ quadb, const float* __restrict__ dot1b,
          const float* __restrict__ b1, const float* __restrict__ gamma,
          const float* __restrict__ beta, float* __restrict__ alpha,
          float* __restrict__ b1p) {
    int o = threadIdx.x;              // single block, 512 threads
    float d1 = dot1b[o], q = quadb[o], b = b1[o];
    float mean = d1 / (float)PTOT + b;
    float eh2  = (q + 2.f * b * d1) / (float)PTOT + b * b;
    float var  = eh2 - mean * mean;
    float al   = gamma[o] * rsqrtf(var + BN_EPS);
    alpha[o] = al;
    b1p[o] = beta[o] + al * (b - mean);
}

// ---------------- K4: features at sampled pixels (alpha folded in epilogue) ----------------
__global__ __launch_bounds__(256)
void kfeat(const float* __restrict__ x, const float* __restrict__ w1,
           const float* __restrict__ alpha, const float* __restrict__ b1p,
           const float* __restrict__ w2, const float* __restrict__ b2,
           const int* __restrict__ batch_idx, const int* __restrict__ pix_idx,
           float* __restrict__ cf, int M, int T, int n_view) {
    __shared__ float xcol[SPB][C_IN];
    __shared__ float h1[SPB][C_IN];
    __shared__ float fl[SPB][C_OUT];
    int tid = threadIdx.x;
    int m0 = blockIdx.x * SPB;

    for (int idx = tid; idx < SPB * C_IN; idx += 256) {
        int s = idx >> 9, c = idx & (C_IN - 1);
        int mm = m0 + s;
        float v = 0.f;
        if (mm < M) {
            int t = mm % T, vv = mm / T;          // cf row m = v*T + t
            int n = batch_idx[t];
            int pix = pix_idx[t * n_view + vv];
            v = x[((size_t)n * C_IN + c) * HW + pix];
        }
        xcol[s][c] = v;
    }
    __syncthreads();

    for (int o = tid; o < C_IN; o += 256) {
        float acc[SPB];
#pragma unroll
        for (int s = 0; s < SPB; ++s) acc[s] = 0.f;
        const float* wrp = w1 + (size_t)o * C_IN;
        for (int c = 0; c < C_IN; c += 4) {
            float4 w = *(const float4*)(wrp + c);
#pragma unroll
            for (int s = 0; s < SPB; ++s) {
                float4 xv = *(const float4*)(&xcol[s][c]);
                acc[s] += w.x * xv.x + w.y * xv.y + w.z * xv.z + w.w * xv.w;
            }
        }
        float al = alpha[o], bb = b1p[o];
#pragma unroll
        for (int s = 0; s < SPB; ++s) h1[s][o] = fmaxf(al * acc[s] + bb, 0.f);
    }
    __syncthreads();

    {
        int j = tid;
        float acc[SPB];
        float bb = b2[j];
#pragma unroll
        for (int s = 0; s < SPB; ++s) acc[s] = bb;
        const float* wrp = w2 + (size_t)j * C_IN;
        for (int o = 0; o < C_IN; o += 4) {
            float4 w = *(const float4*)(wrp + o);
#pragma unroll
            for (int s = 0; s < SPB; ++s) {
                float4 hv = *(const float4*)(&h1[s][o]);
                acc[s] += w.x * hv.x + w.y * hv.y + w.z * hv.z + w.w * hv.w;
            }
        }
#pragma unroll
        for (int s = 0; s < SPB; ++s) fl[s][j] = acc[s];
    }
    __syncthreads();

    int wv = tid >> 6, lane = tid & 63;
    {
        float sq = 0.f;
#pragma unroll
        for (int k = 0; k < 4; ++k) { float v = fl[wv][lane + 64 * k]; sq += v * v; }
        for (int off = 32; off; off >>= 1) sq += __shfl_down(sq, off, 64);
        float nrm = __shfl(sq, 0, 64);
        float rinv = 1.f / fmaxf(sqrtf(nrm), 1e-12f);
        int mm = m0 + wv;
        if (mm < M) {
#pragma unroll
            for (int k = 0; k < 4; ++k)
                cf[(size_t)mm * C_OUT + lane + 64 * k] = fl[wv][lane + 64 * k] * rinv;
        }
    }
}

// ---------------- K5: fused logits + loss, IGRP anchor rows per block ----------------
__global__ __launch_bounds__(256)
void kloss(const float* __restrict__ cf, const int* __restrict__ y_cls,
           float* __restrict__ out, int M, int T) {
    int i0 = blockIdx.x * IGRP;
    int tid = threadIdx.x;
    __shared__ float ci[IGRP][C_OUT];
    __shared__ float row[IGRP][MP];
    __shared__ int   lbl[MP];
    __shared__ float redl[IGRP];
    int lane = tid & 63, wv = tid >> 6;

    for (int idx = tid; idx < IGRP * C_OUT; idx += 256) {
        int g = idx >> 8, c = idx & (C_OUT - 1);
        int ii = i0 + g;
        ci[g][c] = (ii < M) ? cf[(size_t)ii * C_OUT + c] : 0.f;
    }
    for (int j = tid; j < M; j += 256) lbl[j] = y_cls[j % T];
    __syncthreads();

    for (int j = tid; j < M; j += 256) {
        const float* cj = cf + (size_t)j * C_OUT;
        float acc[IGRP];
#pragma unroll
        for (int g = 0; g < IGRP; ++g) acc[g] = 0.f;
        for (int c = 0; c < C_OUT; c += 4) {
            float4 v = *(const float4*)(cj + c);
#pragma unroll
            for (int g = 0; g < IGRP; ++g) {
                float4 cv = *(const float4*)(&ci[g][c]);
                acc[g] += cv.x * v.x + cv.y * v.y + cv.z * v.z + cv.w * v.w;
            }
        }
#pragma unroll
        for (int g = 0; g < IGRP; ++g) row[g][j] = acc[g] * TEMP_INV;
    }
    __syncthreads();

    for (int g = wv; g < IGRP; g += 4) {
        int i = i0 + g;
        if (i < M) {
            int lbl_i = lbl[i];
            const float* r = row[g];

            float mx = -1e30f;
            for (int j = lane; j < M; j += 64) mx = fmaxf(mx, r[j]);
            for (int off = 32; off; off >>= 1) mx = fmaxf(mx, __shfl_down(mx, off, 64));
            mx = __shfl(mx, 0, 64);

            float neg = 0.f;
            for (int j = lane; j < M; j += 64)
                if (lbl[j] != lbl_i) neg += expf(r[j] - mx);
            for (int off = 32; off; off >>= 1) neg += __shfl_down(neg, off, 64);
            neg = __shfl(neg, 0, 64);

            float pos = 0.f; int cnt = 0;
            for (int j = lane; j < M; j += 64) {
                if (lbl[j] == lbl_i && j != i) {
                    float l = r[j] - mx;
                    pos += l - logf(expf(l) + neg);
                    cnt++;
                }
            }
            for (int off = 32; off; off >>= 1) {
                pos += __shfl_down(pos, off, 64);
                cnt += __shfl_down(cnt, off, 64);
            }
            if (lane == 0) redl[g] = -pos / ((float)cnt + 1e-6f);
        } else if (lane == 0) redl[g] = 0.f;
    }
    __syncthreads();
    if (tid == 0) {
        float s = 0.f;
        for (int g = 0; g < IGRP; ++g) s += redl[g];
        atomicAdd(out, s * (0.5f / (float)M));
    }
}

extern "C" void kernel_launch(void* const* d_in, const int* in_sizes, int n_in,
                              void* d_out, int out_size, void* d_ws, size_t ws_size,
                              hipStream_t stream) {
    const float* x     = (const float*)d_in[0];
    const float* w1    = (const float*)d_in[1];
    const float* b1    = (const float*)d_in[2];
    const float* gamma = (const float*)d_in[3];
    const float* beta  = (const float*)d_in[4];
    const float* w2    = (const float*)d_in[5];
    const float* b2    = (const float*)d_in[6];
    const int* batch_idx = (const int*)d_in[7];
    const int* pix_idx   = (const int*)d_in[8];
    const int* y_cls     = (const int*)d_in[9];

    int T = in_sizes[7];
    int M = in_sizes[8];
    int n_view = M / T;

    float* ws    = (float*)d_ws;
    float* s1p   = ws + WS_S1;
    float* G     = ws + WS_G;
    float* quadb = ws + WS_QUAD;
    float* dot1b = ws + WS_DOT1;
    float* alpha = ws + WS_ALPHA;
    float* b1p   = ws + WS_B1P;
    float* cf    = ws + WS_CF;
    __hip_bfloat16* xb = (__hip_bfloat16*)(ws + WS_XB_F);
    float* Gpart = ws + WS_PART_F;

    if (ws_size >= WS_NEED_PART) {
        kprep<<<NIMG * C_IN, 256, 0, stream>>>(x, xb, s1p, quadb, dot1b, (float*)d_out);
        kgram3<<<NTILE * NCHUNK, 256, 0, stream>>>(xb, Gpart);
        kgacc<<<160, 256, 0, stream>>>(Gpart, G);
    } else if (ws_size >= WS_NEED_FAST) {
        hipMemsetAsync(G, 0, (size_t)(C_IN * C_IN) * sizeof(float), stream);
        kprep<<<NIMG * C_IN, 256, 0, stream>>>(x, xb, s1p, quadb, dot1b, (float*)d_out);
        kgram_at<<<dim3(NTILE, NCHUNK), 256, 0, stream>>>(xb, G);
        kmirror<<<C_IN, 256, 0, stream>>>(G);
    } else {
        hipMemsetAsync(G, 0, (size_t)(C_IN * C_IN) * sizeof(float), stream);
        ksum<<<NIMG * C_IN, 256, 0, stream>>>(x, s1p, quadb, dot1b, (float*)d_out);
        kgram_f32<<<dim3(4, 4, 32), 256, 0, stream>>>(x, G);
    }
    kquad<<<dim3(16, 32), 256, 0, stream>>>(G, w1, s1p, quadb, dot1b);
    kfin<<<1, 512, 0, stream>>>(quadb, dot1b, b1, gamma, beta, alpha, b1p);
    kfeat<<<(M + SPB - 1) / SPB, 256, 0, stream>>>(x, w1, alpha, b1p, w2, b2,
                                                   batch_idx, pix_idx, cf, M, T, n_view);
    kloss<<<(M + IGRP - 1) / IGRP, 256, 0, stream>>>(cf, y_cls, (float*)d_out, M, T);
}